// Round 8
// baseline (116.943 us; speedup 1.0000x reference)
//
#include <hip/hip_runtime.h>

#define NN 2048

typedef unsigned short u16;
typedef unsigned char u8;
typedef __attribute__((ext_vector_type(4))) float floatx4;

// fp8 e4m3fn (positive-only domain here) -> f32
__device__ __forceinline__ float fp8_to_f32(unsigned v) {
  const unsigned e = (v >> 3) & 15, m = v & 7;
  const float norm = __uint_as_float(((e + 120u) << 23) | (m << 20));
  const float sub = (float)m * 0.001953125f;  // m * 2^-9
  return e == 0 ? sub : norm;
}

// async global->LDS, 16B per lane. LDS dest = wave-uniform base + lane*16.
__device__ __forceinline__ void load_lds16(const u8* g, u8* l) {
  __builtin_amdgcn_global_load_lds(
      (const __attribute__((address_space(1))) unsigned int*)g,
      (__attribute__((address_space(3))) unsigned int*)l,
      16, 0, 0);
}

// ---------------------------------------------------------------------------
// prep v4 (unchanged, proven): fp32 -> fp8 e4m3 (A8 + A8T), fp32 row-sum
// partials degp[mat][row][32], zero tri. grid (32,32,2), block 256.
// ---------------------------------------------------------------------------
__global__ __launch_bounds__(256) void prep_kernel(
    const float* __restrict__ A1, const float* __restrict__ A2,
    u8* __restrict__ A8, u8* __restrict__ A8T,
    float* __restrict__ degp, float* __restrict__ tri) {
  __shared__ unsigned Tl[64 * 17];
  const int bx = blockIdx.x, by = blockIdx.y, bz = blockIdx.z;
  const float* __restrict__ A = bz ? A2 : A1;
  u8* __restrict__ ab = A8 + (size_t)bz * (NN * (size_t)NN);
  u8* __restrict__ at = A8T + (size_t)bz * (NN * (size_t)NN);
  float* __restrict__ dp = degp + (size_t)bz * (32 * NN);
  const int t = threadIdx.x;
  const int r0 = by * 64, c0 = bx * 64;
  const int q = t >> 4, cs = t & 15;

  if (bx == 0 && t < 64) tri[bz * NN + by * 64 + t] = 0.f;

  unsigned rowpack[4];
#pragma unroll
  for (int d = 0; d < 4; ++d) {
    const int r = 4 * q + d;
    const float4 fv = *(const float4*)(A + (size_t)(r0 + r) * NN + c0 + cs * 4);
    int pk = __builtin_amdgcn_cvt_pk_fp8_f32(fv.x, fv.y, 0, false);
    pk = __builtin_amdgcn_cvt_pk_fp8_f32(fv.z, fv.w, pk, true);
    rowpack[d] = (unsigned)pk;
    *(unsigned*)(ab + (size_t)(r0 + r) * NN + c0 + cs * 4) = (unsigned)pk;
    // exact fp32 row-sum partial over this 64-col slab
    float s = fv.x + fv.y + fv.z + fv.w;
    s += __shfl_xor(s, 1); s += __shfl_xor(s, 2);
    s += __shfl_xor(s, 4); s += __shfl_xor(s, 8);
    if (cs == 0) dp[(size_t)(r0 + r) * 32 + bx] = s;
  }
  // 4x4 byte transpose in registers
#pragma unroll
  for (int e = 0; e < 4; ++e) {
    const unsigned tc = ((rowpack[0] >> (8 * e)) & 0xFFu) |
                        (((rowpack[1] >> (8 * e)) & 0xFFu) << 8) |
                        (((rowpack[2] >> (8 * e)) & 0xFFu) << 16) |
                        (((rowpack[3] >> (8 * e)) & 0xFFu) << 24);
    Tl[(4 * cs + e) * 17 + q] = tc;
  }
  __syncthreads();
#pragma unroll
  for (int p = 0; p < 2; ++p) {
    const int rp = p * 32 + (t >> 3);
    const int mm = t & 7;
    uint2 v;
    v.x = Tl[rp * 17 + 2 * mm];
    v.y = Tl[rp * 17 + 2 * mm + 1];
    *(uint2*)(at + (size_t)(c0 + rp) * NN + r0 + mm * 8) = v;
  }
}

// fp8 MFMA body, 256x256 tile: per wave 8x4 frags of 16x16, 2 K-halves.
// Identical to R7 (order preserved -> bitwise-identical accumulation).
#define MFMA_BODY(PB)                                                      \
  {                                                                        \
    long bL[4][2];                                                         \
    _Pragma("unroll")                                                      \
    for (int tn = 0; tn < 4; ++tn) {                                       \
      bL[tn][0] = *(const long*)(smem + (PB) + boff[tn][0]);               \
      bL[tn][1] = *(const long*)(smem + (PB) + boff[tn][1]);               \
    }                                                                      \
    _Pragma("unroll")                                                      \
    for (int tm = 0; tm < 8; ++tm) {                                       \
      const long a0 = *(const long*)(smem + (PB) + aoff[tm][0]);           \
      const long a1 = *(const long*)(smem + (PB) + aoff[tm][1]);           \
      _Pragma("unroll")                                                    \
      for (int tn = 0; tn < 4; ++tn) {                                     \
        acc[tm][tn] = __builtin_amdgcn_mfma_f32_16x16x32_fp8_fp8(          \
            a0, bL[tn][0], acc[tm][tn], 0, 0, 0);                          \
        acc[tm][tn] = __builtin_amdgcn_mfma_f32_16x16x32_fp8_fp8(          \
            a1, bL[tn][1], acc[tm][tn], 0, 0, 0);                          \
      }                                                                    \
    }                                                                      \
  }

#define PREFETCH(KK, DB)                                                   \
  load_lds16(gA0 + (KK), smem + (DB) + sA0);                               \
  load_lds16(gA1 + (KK), smem + (DB) + sA1);                               \
  load_lds16(gB0 + (KK), smem + (DB) + sB0);                               \
  load_lds16(gB1 + (KK), smem + (DB) + sB1);

#define FENCE asm volatile("" ::: "memory")
#define BARRIER FENCE; __builtin_amdgcn_s_barrier(); FENCE

// ---------------------------------------------------------------------------
// gemm_tri fp8, 256x256 tile, DEPTH-2 pipeline (R7 post-mortem): gemm time
// is invariant to MFMA rate, staged bytes, cache warmth, and L2 locality
// (R0-R7) -> the binding constraint is depth-1 prefetch: every step exposes
// the full issue->L2->LDS latency behind the block barrier (guide m233).
// Minimal delta on the proven R7 kernel: 3 buffers (96 KB LDS), issue step
// t+2, vmcnt(8) steady state (own loads done, 8 newer in flight) -> latency
// budget = 2 steps. ROLLED 3-phase loop (buffer = phase, compile-time bases;
// pointers bump +192/iter) -- R3's spill failure came from full unroll, not
// depth. Barriers/swizzles/MFMA order byte-for-byte R7.
// grid (8,8,4), block 512 (8 waves, 2x4), split-K=2, 1 block/CU.
// ---------------------------------------------------------------------------
__global__ __launch_bounds__(512, 2) void gemm_tri_kernel(
    const u8* __restrict__ A8, const u8* __restrict__ A8T,
    float* __restrict__ tri) {
  // buf p at [p*32768, +32768): As 16 KB + Bs 16 KB, p = 0,1,2.
  // epilogue reuses [0, 256*272=69632) as T tile (pitch 272).
  __shared__ __align__(16) u8 smem[98304];

  const int tid = threadIdx.x;
  const int w = tid >> 6, lane = tid & 63;
  const int wm = w >> 2, wn = w & 3;  // 2 x 4 wave grid
  const int cl = lane & 15, g = lane >> 4;
  const int bx = blockIdx.x, by = blockIdx.y, bz = blockIdx.z;
  const int i0 = by * 256, j0 = bx * 256;
  const int mz = bz >> 1, kz = bz & 1;
  const size_t mat = (size_t)mz * (NN * (size_t)NN);
  const u8* __restrict__ Am = A8 + mat;
  const u8* __restrict__ ATm = A8T + mat;
  float* __restrict__ triM = tri + mz * NN;

  // staging: 16 KB/operand/step = 1024 slots of 16 B; wave w owns slots
  // w*128 + lane and w*128+64+lane. slot s -> row = s>>2 (64 B rows),
  // stored chunk c' = s&3 holds global chunk c'^((row>>1)&3).
  const int s0 = w * 128 + lane;
  const int s1 = w * 128 + 64 + lane;
  const int r0s = s0 >> 2, c0s = (s0 & 3) ^ ((r0s >> 1) & 3);
  const int r1s = s1 >> 2, c1s = (s1 & 3) ^ ((r1s >> 1) & 3);
  const int kbase = kz * 1024;  // bytes along K (split-K half)
  const u8* gA0 = Am + (size_t)(i0 + r0s) * NN + kbase + c0s * 16;
  const u8* gA1 = Am + (size_t)(i0 + r1s) * NN + kbase + c1s * 16;
  const u8* gB0 = ATm + (size_t)(j0 + r0s) * NN + kbase + c0s * 16;
  const u8* gB1 = ATm + (size_t)(j0 + r1s) * NN + kbase + c1s * 16;
  const int sA0 = w * 2048, sA1 = w * 2048 + 1024;
  const int sB0 = 16384 + sA0, sB1 = 16384 + sA1;

  // fragment read offsets (bytes within buffer): frag row r, K-half h needs
  // bytes 32h + g*8 .. +7 -> chunk 2h + (g>>1) (XOR-swizzled), sub (g&1)*8.
  const int rsw = (cl >> 1) & 3;
  const int sub = (g & 1) * 8, ch = g >> 1;
  int aoff[8][2], boff[4][2];
#pragma unroll
  for (int tm = 0; tm < 8; ++tm) {
    const int r = wm * 128 + tm * 16 + cl;
#pragma unroll
    for (int h = 0; h < 2; ++h)
      aoff[tm][h] = r * 64 + (((2 * h + ch) ^ rsw) * 16) + sub;
  }
#pragma unroll
  for (int tn = 0; tn < 4; ++tn) {
    const int r = wn * 64 + tn * 16 + cl;
#pragma unroll
    for (int h = 0; h < 2; ++h)
      boff[tn][h] = 16384 + r * 64 + (((2 * h + ch) ^ rsw) * 16) + sub;
  }

  floatx4 acc[8][4] = {};

  // prologue: steps 0,1 -> bufs 0,1 (8 loads in flight per wave)
  PREFETCH(0, 0)
  PREFETCH(64, 32768)

  // steady state: step t issues t+2 into buf (t+2)%3, waits vmcnt(8) (own 4
  // loads done, 8 newer outstanding), computes buf t%3. 3-phase rolled body:
  // phase p handles t = 3d+p -> buffer index = p (compile-time). Pointers
  // advance by 3*64 per iteration; in-iter offsets 128/192/256 constant.
  // Hazard: issue target buf (t+2)%3 == buf of step t-1, whose reads finish
  // before this step's top barrier.
#pragma unroll 1
  for (int d = 0; d < 4; ++d) {
    // t = 3d+0: compute buf0, issue step 3d+2 -> buf2
    BARRIER;
    PREFETCH(128, 65536)
    __builtin_amdgcn_s_waitcnt(0x0F78);  // vmcnt(8)
    BARRIER;
    MFMA_BODY(0)
    // t = 3d+1: compute buf1, issue step 3d+3 -> buf0
    BARRIER;
    PREFETCH(192, 0)
    __builtin_amdgcn_s_waitcnt(0x0F78);  // vmcnt(8)
    BARRIER;
    MFMA_BODY(32768)
    // t = 3d+2: compute buf2, issue step 3d+4 -> buf1
    BARRIER;
    PREFETCH(256, 32768)
    __builtin_amdgcn_s_waitcnt(0x0F78);  // vmcnt(8)
    BARRIER;
    MFMA_BODY(65536)
    gA0 += 192; gA1 += 192; gB0 += 192; gB1 += 192;
  }
  // tail: t=12 (compute buf0, issue step 14 -> buf2; rel offset 896-768=128)
  BARRIER;
  PREFETCH(128, 65536)
  __builtin_amdgcn_s_waitcnt(0x0F78);  // vmcnt(8)
  BARRIER;
  MFMA_BODY(0)
  // t=13 (compute buf1, issue step 15 -> buf0; rel offset 960-768=192)
  BARRIER;
  PREFETCH(192, 0)
  __builtin_amdgcn_s_waitcnt(0x0F78);  // vmcnt(8)
  BARRIER;
  MFMA_BODY(32768)
  // t=14 (compute buf2; step-14 loads done when 4 remain)
  BARRIER;
  __builtin_amdgcn_s_waitcnt(0x0F74);  // vmcnt(4)
  BARRIER;
  MFMA_BODY(65536)
  // t=15 (compute buf0, drain)
  BARRIER;
  __builtin_amdgcn_s_waitcnt(0x0F70);  // vmcnt(0)
  BARRIER;
  MFMA_BODY(0)

  // epilogue: tri[i0+r] += sum_c C[r][c] * A^T[i0+r][j0+c]
  __syncthreads();
  // stage T: 256 rows x 256 B fp8, pitch 272 (16B-aligned, bank-spread)
#pragma unroll
  for (int it = 0; it < 8; ++it) {
    const int idx = tid + it * 512;
    const int r = idx >> 4, co = (idx & 15) * 16;
    *(uint4*)(smem + r * 272 + co) =
        *(const uint4*)(ATm + (size_t)(i0 + r) * NN + j0 + co);
  }
  __syncthreads();

#pragma unroll
  for (int tm = 0; tm < 8; ++tm) {
#pragma unroll
    for (int reg = 0; reg < 4; ++reg) {
      const int rloc = wm * 128 + tm * 16 + g * 4 + reg;  // C/D row
      float v = 0.f;
#pragma unroll
      for (int tn = 0; tn < 4; ++tn) {
        const int cloc = wn * 64 + tn * 16 + cl;          // C/D col
        v += acc[tm][tn][reg] * fp8_to_f32(smem[rloc * 272 + cloc]);
      }
      v += __shfl_xor(v, 1);
      v += __shfl_xor(v, 2);
      v += __shfl_xor(v, 4);
      v += __shfl_xor(v, 8);
      if (cl == 0) atomicAdd(&triM[i0 + rloc], v);
    }
  }
}

// ---------------------------------------------------------------------------
// finalize stage 1: grid 16 x 1024 threads; block b reduces rows [b*128,+128).
// ---------------------------------------------------------------------------
__global__ __launch_bounds__(1024) void finalize1_kernel(
    const float* __restrict__ degp, const float* __restrict__ tri,
    float* __restrict__ part) {
  __shared__ float red[32];
  const int t = threadIdx.x;
  const int r = blockIdx.x * 128 + (t >> 3);   // row
  const int q = (t & 7) * 4;                   // degp chunk
  const float4 v1 = *(const float4*)(degp + (size_t)r * 32 + q);
  const float4 v2 = *(const float4*)(degp + 32 * NN + (size_t)r * 32 + q);
  float d1 = v1.x + v1.y + v1.z + v1.w;
  float d2 = v2.x + v2.y + v2.z + v2.w;
#pragma unroll
  for (int m = 1; m < 8; m <<= 1) {
    d1 += __shfl_xor(d1, m);
    d2 += __shfl_xor(d2, m);
  }
  float sdd = 0.f, scc = 0.f;
  if ((t & 7) == 0) {
    const float t1 = tri[r], t2 = tri[NN + r];
    const float e1 = d1 < 2.f ? 1.f : d1;
    const float e2 = d2 < 2.f ? 1.f : d2;
    sdd = fabsf(d1 - d2);
    scc = fabsf(t1 / (e1 * (e1 - 1.f)) - t2 / (e2 * (e2 - 1.f)));
  }
#pragma unroll
  for (int m = 8; m < 64; m <<= 1) {
    sdd += __shfl_xor(sdd, m);
    scc += __shfl_xor(scc, m);
  }
  const int wv = t >> 6, ln = t & 63;
  if (ln == 0) { red[wv] = sdd; red[16 + wv] = scc; }
  __syncthreads();
  if (t == 0) {
    float a = 0.f, b = 0.f;
#pragma unroll
    for (int i = 0; i < 16; ++i) { a += red[i]; b += red[16 + i]; }
    part[blockIdx.x * 2 + 0] = a;
    part[blockIdx.x * 2 + 1] = b;
  }
}

__global__ void finalize2_kernel(const float* __restrict__ part,
                                 float* __restrict__ out) {
  if (threadIdx.x == 0) {
    float a = 0.f, b = 0.f;
#pragma unroll
    for (int i = 0; i < 16; ++i) { a += part[i * 2]; b += part[i * 2 + 1]; }
    const float ds = expf(-a * (1.f / (float)NN));
    const float cs = expf(-b * (1.f / (float)NN));
    out[0] = ds;
    out[1] = cs;
    out[2] = 0.5f * (ds + cs);
  }
}

extern "C" void kernel_launch(void* const* d_in, const int* in_sizes, int n_in,
                              void* d_out, int out_size, void* d_ws, size_t ws_size,
                              hipStream_t stream) {
  (void)in_sizes; (void)n_in; (void)out_size; (void)ws_size;
  const float* A1 = (const float*)d_in[0];
  const float* A2 = (const float*)d_in[1];
  float* out = (float*)d_out;

  // workspace layout:
  //   A8   [2][2048*2048] u8  : 8 MB
  //   A8T  [2][2048*2048] u8  : 8 MB
  //   tri  [2][2048] f32
  //   degp [2][2048][32] f32
  //   part [32] f32
  u8* A8 = (u8*)d_ws;
  u8* A8T = A8 + 2 * (size_t)NN * NN;
  float* tri = (float*)(A8T + 2 * (size_t)NN * NN);
  float* degp = tri + 2 * NN;
  float* part = degp + 2 * 32 * NN;

  prep_kernel<<<dim3(32, 32, 2), 256, 0, stream>>>(A1, A2, A8, A8T, degp, tri);
  gemm_tri_kernel<<<dim3(8, 8, 4), 512, 0, stream>>>(A8, A8T, tri);
  finalize1_kernel<<<16, 1024, 0, stream>>>(degp, tri, part);
  finalize2_kernel<<<1, 64, 0, stream>>>(part, out);
}